// Round 5
// baseline (418.149 us; speedup 1.0000x reference)
//
#include <hip/hip_runtime.h>
#include <cstddef>
#include <cstdint>

#define LEN_T 11253
#define TOK   22506     // BS * LEN
#define NHEADS 8
#define DMODEL 256

typedef __attribute__((ext_vector_type(8))) short short8;   // bf16x8 (4 VGPR)
typedef __attribute__((ext_vector_type(4))) float f32x4;

__device__ __forceinline__ unsigned short f2bf(float f) {
  union { float f; unsigned u; } v; v.f = f;
  unsigned r = v.u + 0x7fffu + ((v.u >> 16) & 1u);   // RNE
  return (unsigned short)(r >> 16);
}
__device__ __forceinline__ float bfhi2f(unsigned u) {
  union { unsigned u; float f; } v; v.u = u & 0xffff0000u; return v.f;
}
__device__ __forceinline__ float bflo2f(unsigned u) {
  union { unsigned u; float f; } v; v.u = u << 16; return v.f;
}
__device__ __forceinline__ void gld_lds16(const void* g, void* l) {
  __builtin_amdgcn_global_load_lds(
      (const __attribute__((address_space(1))) void*)g,
      (__attribute__((address_space(3))) void*)l, 16, 0, 0);
}

// branchless stable top-4 insert (desc, strict > : earlier index wins ties)
__device__ __forceinline__ void ins4(float v, int ji,
    float& t0, float& t1, float& t2, float& t3,
    int& i0, int& i1, int& i2, int& i3)
{
  bool a0 = v > t0, a1 = v > t1, a2 = v > t2, a3 = v > t3;
  t3 = a3 ? (a2 ? t2 : v) : t3;  i3 = a3 ? (a2 ? i2 : ji) : i3;
  t2 = a2 ? (a1 ? t1 : v) : t2;  i2 = a2 ? (a1 ? i1 : ji) : i2;
  t1 = a1 ? (a0 ? t0 : v) : t1;  i1 = a1 ? (a0 ? i0 : ji) : i1;
  t0 = a0 ? v : t0;              i0 = a0 ? ji : i0;
}

// ============ pre-kernel: per-token top/bot scan + heads + weight casts =====
// blocks [0,88): token scan -> offp/attw per (token, head)
// blocks [88,728): weight cast+transpose, 4 elems/thread
__global__ __launch_bounds__(256) void pre_kernel(
    const float* __restrict__ m0, const float* __restrict__ m1,
    const float* __restrict__ m2, const float* __restrict__ m3,
    const float* __restrict__ pm_w, const float* __restrict__ pm_b,
    const float* __restrict__ Wv, const float* __restrict__ Wo,
    const float* __restrict__ W1, const float* __restrict__ W2,
    unsigned short* __restrict__ Wv_t, unsigned short* __restrict__ Wo_t,
    unsigned short* __restrict__ W1_t, unsigned short* __restrict__ W2_t,
    unsigned* __restrict__ offp, float* __restrict__ attw)
{
  int blk = blockIdx.x;
  if (blk >= 88) {   // ---- weight cast+transpose: Bt[n][k] = bf16(W[k][n])
    int cb = blk - 88;
    const float* W; unsigned short* Bt; int lk, ln, base;
    if (cb < 64)       { W = Wv; Bt = Wv_t; lk = 8;  ln = 8;  base = cb; }
    else if (cb < 128) { W = Wo; Bt = Wo_t; lk = 8;  ln = 8;  base = cb - 64; }
    else if (cb < 384) { W = W1; Bt = W1_t; lk = 8;  ln = 10; base = cb - 128; }
    else               { W = W2; Bt = W2_t; lk = 10; ln = 8;  base = cb - 384; }
    int i4 = (base * 256 + threadIdx.x) * 4;
    int n  = i4 >> lk;
    int k  = i4 & ((1 << lk) - 1);
    ushort4 o;
    o.x = f2bf(W[((size_t)(k + 0) << ln) + n]);
    o.y = f2bf(W[((size_t)(k + 1) << ln) + n]);
    o.z = f2bf(W[((size_t)(k + 2) << ln) + n]);
    o.w = f2bf(W[((size_t)(k + 3) << ln) + n]);
    *(ushort4*)(Bt + i4) = o;
    return;
  }
  int tok = blk * 256 + threadIdx.x;
  if (tok >= TOK) return;
  int b = tok >= LEN_T;
  int q = tok - b * LEN_T;
  int l, H_, W_;
  const float* mk;
  if (q < 8464)       { l = 0; H_ = 92; W_ = 92; mk = m0; }
  else if (q < 10580) { l = 1; H_ = 46; W_ = 46; mk = m1; }
  else if (q < 11109) { l = 2; H_ = 23; W_ = 23; mk = m2; }
  else                { l = 3; H_ = 12; W_ = 12; mk = m3; }
  int st = (l == 0) ? 0 : (l == 1) ? 8464 : (l == 2) ? 10580 : 11109;
  int pos = q - st;
  int rr = pos / W_;
  int cc = pos - rr * W_;
  const float* mp = mk + (size_t)b * H_ * W_;
  bool interior = (rr >= 3) && (rr + 3 < H_) && (cc >= 3) && (cc + 3 < W_);

  if (interior) {
    // shared scan in mask space: top4 and bot4 (bot via negation, stable)
    float t0=-1e30f,t1=-1e30f,t2=-1e30f,t3=-1e30f; int ti0=0,ti1=0,ti2=0,ti3=0;
    float n0=-1e30f,n1=-1e30f,n2=-1e30f,n3=-1e30f; int bi0=0,bi1=0,bi2=0,bi3=0;
    for (int i = 0; i < 7; ++i) {
      const float* rowp = mp + (size_t)(rr + i - 3) * W_ + cc - 3;
      #pragma unroll
      for (int j = 0; j < 7; ++j) {
        float v = rowp[j];
        int ji = j | (i << 4);
        ins4(v,  ji, t0, t1, t2, t3, ti0, ti1, ti2, ti3);
        ins4(-v, ji, n0, n1, n2, n3, bi0, bi1, bi2, bi3);
      }
    }
    unsigned pkt = (unsigned)ti0 | ((unsigned)ti1 << 8) | ((unsigned)ti2 << 16) | ((unsigned)ti3 << 24);
    unsigned pkb = (unsigned)bi0 | ((unsigned)bi1 << 8) | ((unsigned)bi2 << 16) | ((unsigned)bi3 << 24);
    #pragma unroll
    for (int h = 0; h < 8; ++h) {
      float w = pm_w[l * NHEADS + h];
      bool neg = w < 0.f;
      float v0 = neg ? -n0 : t0, v1 = neg ? -n1 : t1;
      float v2 = neg ? -n2 : t2, v3 = neg ? -n3 : t3;
      float e1 = __expf(w * (v1 - v0));
      float e2 = __expf(w * (v2 - v0));
      float e3 = __expf(w * (v3 - v0));
      float inv = 1.f / (4.f * (1.f + e1 + e2 + e3));
      float4 wout; wout.x = inv; wout.y = e1 * inv; wout.z = e2 * inv; wout.w = e3 * inv;
      *(float4*)(attw + ((size_t)tok * 8 + h) * 4) = wout;
      offp[(size_t)tok * 8 + h] = neg ? pkb : pkt;
    }
  } else {
    // exact per-head scan in m-space (padding = 0 post-conv)
    #pragma unroll 1
    for (int h = 0; h < 8; ++h) {
      float w  = pm_w[l * NHEADS + h];
      float bb = pm_b[l * NHEADS + h];
      float t0=-1e30f,t1=-1e30f,t2=-1e30f,t3=-1e30f; int i0=0,i1=0,i2=0,i3=0;
      for (int i = 0; i < 7; ++i) {
        int yy = rr + i - 3;
        #pragma unroll
        for (int j = 0; j < 7; ++j) {
          int xx = cc + j - 3;
          float v = 0.f;
          if (yy >= 0 && yy < H_ && xx >= 0 && xx < W_)
            v = mp[(size_t)yy * W_ + xx] * w + bb;
          ins4(v, j | (i << 4), t0, t1, t2, t3, i0, i1, i2, i3);
        }
      }
      float e1 = __expf(t1 - t0);
      float e2 = __expf(t2 - t0);
      float e3 = __expf(t3 - t0);
      float inv = 1.f / (4.f * (1.f + e1 + e2 + e3));
      float4 wout; wout.x = inv; wout.y = e1 * inv; wout.z = e2 * inv; wout.w = e3 * inv;
      *(float4*)(attw + ((size_t)tok * 8 + h) * 4) = wout;
      offp[(size_t)tok * 8 + h] = (unsigned)i0 | ((unsigned)i1 << 8)
                                | ((unsigned)i2 << 16) | ((unsigned)i3 << 24);
    }
  }
}

// ---------------- deformable bilinear sampling (bf16 V, v2) ----------------
// 2 tokens per wave (8/block), 16B gathers, indices preloaded to registers.
// grid MUST be 2814 blocks; XCD-contiguous swizzle (8 XCDs, 2814 = 8*351+6).
__global__ __launch_bounds__(256, 3) void sample_kernel(
    const unsigned short* __restrict__ Vb, const float* __restrict__ refpts,
    const unsigned* __restrict__ offp, const float* __restrict__ attw,
    unsigned short* __restrict__ outp)
{
  __shared__ ushort4 sidx[4][2][128];   //  8 KB
  __shared__ float4  swgt[4][2][128];   // 16 KB
  const int wv   = threadIdx.x >> 6;
  const int lane = threadIdx.x & 63;
  const int bx = blockIdx.x & 7, by = blockIdx.x >> 3;
  const int nb = bx * 351 + min(bx, 6) + by;
  const int base = nb * 8;              // first token of this block

  #pragma unroll
  for (int e = 0; e < 4; ++e) {
    int g  = lane * 4 + e;              // 0..255
    int tk = g >> 7, t = g & 127;       // t = lp*8 + h
    int token = base + wv * 2 + tk;
    ushort4 idx; idx.x = 0; idx.y = 0; idx.z = 0; idx.w = 0;
    float4  wg;  wg.x = 0.f; wg.y = 0.f; wg.z = 0.f; wg.w = 0.f;
    if (token < TOK) {
      int h = t & 7, lp = t >> 3, lev = lp >> 2, p = lp & 3;
      int b = token >= LEN_T;
      unsigned pb = (offp[(size_t)token * 8 + h] >> (8 * p)) & 0xffu;
      float aw = attw[((size_t)token * 8 + h) * 4 + p];
      float ox = (float)(int)(pb & 15u) - 3.f;
      float oy = (float)(int)(pb >> 4)  - 3.f;
      int H_ = (lev == 0) ? 92 : (lev == 1) ? 46 : (lev == 2) ? 23 : 12;
      int st = (lev == 0) ? 0  : (lev == 1) ? 8464 : (lev == 2) ? 10580 : 11109;
      const float* rp = refpts + (size_t)token * 8;
      float xx = rp[2 * lev]     * (float)H_ - 0.5f + ox;
      float yy = rp[2 * lev + 1] * (float)H_ - 0.5f + oy;
      float x0f = floorf(xx), y0f = floorf(yy);
      float tx = xx - x0f, ty = yy - y0f;
      int x0 = (int)x0f, y0 = (int)y0f;
      int vbase = b * LEN_T + st;
      float wc[4] = {(1.f - tx) * (1.f - ty), tx * (1.f - ty),
                     (1.f - tx) * ty,         tx * ty};
      int xs[4] = {x0, x0 + 1, x0, x0 + 1};
      int ys[4] = {y0, y0, y0 + 1, y0 + 1};
      int id[4]; float wt[4];
      #pragma unroll
      for (int c = 0; c < 4; ++c) {
        int xi = xs[c], yi = ys[c];
        bool v_ = (xi >= 0) & (xi < H_) & (yi >= 0) & (yi < H_);
        id[c] = vbase + min(max(yi, 0), H_ - 1) * H_ + min(max(xi, 0), H_ - 1);
        wt[c] = v_ ? aw * wc[c] : 0.f;
      }
      idx.x = (unsigned short)id[0]; idx.y = (unsigned short)id[1];
      idx.z = (unsigned short)id[2]; idx.w = (unsigned short)id[3];
      wg.x = wt[0]; wg.y = wt[1]; wg.z = wt[2]; wg.w = wt[3];
    }
    sidx[wv][tk][t] = idx;
    swgt[wv][tk][t] = wg;
  }
  __syncthreads();

  const int tk2 = lane >> 5;
  const int h2  = (lane >> 2) & 7;
  const int dg  = lane & 3;
  const int token = base + wv * 2 + tk2;
  ushort4 si[16];
  #pragma unroll
  for (int lp = 0; lp < 16; ++lp) si[lp] = sidx[wv][tk2][lp * 8 + h2];
  const unsigned short* vb = Vb + h2 * 32 + dg * 8;   // 8 bf16 = 16B per lane
  f32x4 aA = {0.f, 0.f, 0.f, 0.f}, aB = {0.f, 0.f, 0.f, 0.f};
  #pragma unroll
  for (int lp = 0; lp < 16; ++lp) {
    float4 wg = swgt[wv][tk2][lp * 8 + h2];
    uint4 u0 = *(const uint4*)(vb + (size_t)si[lp].x * DMODEL);
    uint4 u1 = *(const uint4*)(vb + (size_t)si[lp].y * DMODEL);
    uint4 u2 = *(const uint4*)(vb + (size_t)si[lp].z * DMODEL);
    uint4 u3 = *(const uint4*)(vb + (size_t)si[lp].w * DMODEL);
    aA.x += wg.x*bflo2f(u0.x) + wg.y*bflo2f(u1.x) + wg.z*bflo2f(u2.x) + wg.w*bflo2f(u3.x);
    aA.y += wg.x*bfhi2f(u0.x) + wg.y*bfhi2f(u1.x) + wg.z*bfhi2f(u2.x) + wg.w*bfhi2f(u3.x);
    aA.z += wg.x*bflo2f(u0.y) + wg.y*bflo2f(u1.y) + wg.z*bflo2f(u2.y) + wg.w*bflo2f(u3.y);
    aA.w += wg.x*bfhi2f(u0.y) + wg.y*bfhi2f(u1.y) + wg.z*bfhi2f(u2.y) + wg.w*bfhi2f(u3.y);
    aB.x += wg.x*bflo2f(u0.z) + wg.y*bflo2f(u1.z) + wg.z*bflo2f(u2.z) + wg.w*bflo2f(u3.z);
    aB.y += wg.x*bfhi2f(u0.z) + wg.y*bfhi2f(u1.z) + wg.z*bfhi2f(u2.z) + wg.w*bfhi2f(u3.z);
    aB.z += wg.x*bflo2f(u0.w) + wg.y*bflo2f(u1.w) + wg.z*bflo2f(u2.w) + wg.w*bflo2f(u3.w);
    aB.w += wg.x*bfhi2f(u0.w) + wg.y*bfhi2f(u1.w) + wg.z*bfhi2f(u2.w) + wg.w*bfhi2f(u3.w);
  }
  if (token < TOK) {
    uint4 o;
    o.x = (unsigned)f2bf(aA.x) | ((unsigned)f2bf(aA.y) << 16);
    o.y = (unsigned)f2bf(aA.z) | ((unsigned)f2bf(aA.w) << 16);
    o.z = (unsigned)f2bf(aB.x) | ((unsigned)f2bf(aB.y) << 16);
    o.w = (unsigned)f2bf(aB.z) | ((unsigned)f2bf(aB.w) << 16);
    *(uint4*)(outp + (size_t)token * DMODEL + h2 * 32 + dg * 8) = o;
  }
}

// ============ B-resident MFMA GEMM, K = KC*256 ==============================
// C[M,N] = A[M,K] @ Bt[N,K]^T (+bias...). B fragments resident in VGPRs per
// 256-k chunk (8 kc x 4 nt x short8 = 128 VGPR); A double-buffered via LDS.
// Block = 64 rows x 256 cols, 4 waves, wave tile 64x64 (4x4 of 16x16x32).
// EPI 0: Cb = bf16(acc + bias)
// EPI 1: LN(acc + bias + res) -> C f32 AND Cb bf16   (N must be 256)
// EPI 2: Cb = bf16(relu(acc + bias))
// EPI 3: LN(acc + bias + res) -> C f32 only          (N must be 256)
// AF32: A is f32, cast to bf16 inline during staging.
template<int EPI, bool AF32, int KC>
__global__ __launch_bounds__(256, 2) void gemm_bres(
    const void* __restrict__ Aptr, const short* __restrict__ Bt,
    const float* __restrict__ bias, const float* __restrict__ res,
    const float* __restrict__ lng, const float* __restrict__ lnb,
    float* __restrict__ C, unsigned short* __restrict__ Cb,
    int M, int N)
{
  constexpr int K = KC * 256;
  __shared__ short As[2][64 * 32] __attribute__((aligned(16)));  // 2 x 4 KB
  __shared__ float2 lnred[64][4];
  const int tid  = threadIdx.x;
  const int w    = tid >> 6;
  const int lane = tid & 63;
  const int row0 = blockIdx.x * 64;
  const int wn   = blockIdx.y * 256 + w * 64;   // this wave's 64 output cols
  const int colq = lane & 15, quad = lane >> 4;
  const int kq8  = quad * 8;

  short8 bq[8][4];
  auto loadB = [&](int c) {
    #pragma unroll
    for (int kc = 0; kc < 8; ++kc)
      #pragma unroll
      for (int nt = 0; nt < 4; ++nt)
        bq[kc][nt] = *(const short8*)(Bt + (size_t)(wn + nt * 16 + colq) * K
                                         + c * 256 + kc * 32 + kq8);
  };

  f32x4 acc[4][4];
  #pragma unroll
  for (int i = 0; i < 4; ++i)
    #pragma unroll
    for (int j = 0; j < 4; ++j) acc[i][j] = (f32x4){0.f, 0.f, 0.f, 0.f};

  const int rA  = min(row0 + (tid >> 2), M - 1);
  const int kq4 = (tid & 3) * 8;
  const float* Af = (const float*)Aptr;
  const short* Ab = (const short*)Aptr;

  auto stageA = [&](int kbg, int nbuf) {
    if constexpr (AF32) {
      const float* ap = Af + (size_t)rA * K + kbg * 32 + kq4;
      float4 f0 = *(const float4*)ap;
      float4 f1 = *(const float4*)(ap + 4);
      uint4 u;
      u.x = (unsigned)f2bf(f0.x) | ((unsigned)f2bf(f0.y) << 16);
      u.y = (unsigned)f2bf(f0.z) | ((unsigned)f2bf(f0.w) << 16);
      u.z = (unsigned)f2bf(f1.x) | ((unsigned)f2bf(f1.y) << 16);
      u.w = (unsigned)f2bf(f1.z) | ((unsigned)f2bf(f1.w) << 16);
      *(uint4*)(As[nbuf] + (size_t)tid * 8) = u;
    } else {
      gld_lds16(Ab + (size_t)rA * K + kbg * 32 + kq4, As[nbuf] + (size_t)tid * 8);
    }
  };

  stageA(0, 0);
  loadB(0);
  __syncthreads();
  int buf = 0;
  #pragma unroll
  for (int c = 0; c < KC; ++c) {
    if (c > 0) loadB(c);
    #pragma unroll
    for (int kb = 0; kb < 8; ++kb) {
      const int kbg = c * 8 + kb;
      if (kbg < KC * 8 - 1) stageA(kbg + 1, buf ^ 1);
      short8 af[4];
      #pragma unroll
      for (int mt = 0; mt < 4; ++mt)
        af[mt] = *(const short8*)(As[buf] + (size_t)(mt * 16 + colq) * 32 + kq8);
      #pragma unroll
      for (int mt = 0; mt < 4; ++mt)
        #pragma unroll
        for (int nt = 0; nt < 4; ++nt)
          acc[mt][nt] = __builtin_amdgcn_mfma_f32_16x16x32_bf16(
              af[mt], bq[kb][nt], acc[mt][nt], 0, 0, 0);
      __syncthreads();
      buf ^= 1;
    }
  }

  // ---- epilogue: C/D layout col = lane&15, row = quad*4 + reg ----
  float bia[4];
  #pragma unroll
  for (int nt = 0; nt < 4; ++nt) bia[nt] = bias[wn + nt * 16 + colq];

  if constexpr (EPI == 1 || EPI == 3) {
    #pragma unroll
    for (int mt = 0; mt < 4; ++mt) {
      #pragma unroll
      for (int r = 0; r < 4; ++r) {
        int lrow = mt * 16 + quad * 4 + r;
        int rowc = min(row0 + lrow, M - 1);
        float s = 0.f, sq = 0.f;
        #pragma unroll
        for (int nt = 0; nt < 4; ++nt) {
          float f = acc[mt][nt][r] + bia[nt]
                  + res[(size_t)rowc * 256 + wn + nt * 16 + colq];
          acc[mt][nt][r] = f;
          s += f; sq += f * f;
        }
        #pragma unroll
        for (int off = 1; off < 16; off <<= 1) {
          s  += __shfl_xor(s,  off, 64);
          sq += __shfl_xor(sq, off, 64);
        }
        if (colq == 0) lnred[lrow][w] = (float2){s, sq};
      }
    }
    __syncthreads();
    #pragma unroll
    for (int mt = 0; mt < 4; ++mt) {
      #pragma unroll
      for (int r = 0; r < 4; ++r) {
        int lrow = mt * 16 + quad * 4 + r;
        int row  = row0 + lrow;
        if (row >= M) continue;
        float2 p0 = lnred[lrow][0], p1 = lnred[lrow][1];
        float2 p2 = lnred[lrow][2], p3 = lnred[lrow][3];
        float mu  = (p0.x + p1.x + p2.x + p3.x) * (1.f / 256.f);
        float var = (p0.y + p1.y + p2.y + p3.y) * (1.f / 256.f) - mu * mu;
        float rs  = rsqrtf(var + 1e-5f);          // biased var (jnp.var)
        #pragma unroll
        for (int nt = 0; nt < 4; ++nt) {
          int col = wn + nt * 16 + colq;
          float o = (acc[mt][nt][r] - mu) * rs * lng[col] + lnb[col];
          C[(size_t)row * 256 + col] = o;
          if constexpr (EPI == 1)
            Cb[(size_t)row * 256 + col] = f2bf(o);
        }
      }
    }
  } else {
    #pragma unroll
    for (int mt = 0; mt < 4; ++mt) {
      #pragma unroll
      for (int r = 0; r < 4; ++r) {
        int row = row0 + mt * 16 + quad * 4 + r;
        if (row < M) {
          #pragma unroll
          for (int nt = 0; nt < 4; ++nt) {
            float f = acc[mt][nt][r] + bia[nt];
            if constexpr (EPI == 2) f = fmaxf(f, 0.f);
            Cb[(size_t)row * N + wn + nt * 16 + colq] = f2bf(f);
          }
        }
      }
    }
  }
}

extern "C" void kernel_launch(void* const* d_in, const int* in_sizes, int n_in,
                              void* d_out, int out_size, void* d_ws, size_t ws_size,
                              hipStream_t stream)
{
  const float* src    = (const float*)d_in[0];
  const float* refpts = (const float*)d_in[2];
  const float* m0   = (const float*)d_in[4];
  const float* m1   = (const float*)d_in[5];
  const float* m2   = (const float*)d_in[6];
  const float* m3   = (const float*)d_in[7];
  const float* pm_w = (const float*)d_in[10];
  const float* pm_b = (const float*)d_in[11];
  const float* Wv   = (const float*)d_in[12];
  const float* bv   = (const float*)d_in[13];
  const float* Wo   = (const float*)d_in[14];
  const float* bo   = (const float*)d_in[15];
  const float* ln1g = (const float*)d_in[16];
  const float* ln1b = (const float*)d_in[17];
  const float* W1   = (const float*)d_in[18];
  const float* b1   = (const float*)d_in[19];
  const float* W2   = (const float*)d_in[20];
  const float* b2   = (const float*)d_in[21];
  const float* ln2g = (const float*)d_in[22];
  const float* ln2b = (const float*)d_in[23];
  float* out = (float*)d_out;
  char*  w   = (char*)d_ws;

  const bool big = ws_size >= 97096256ull;          // full-batch h1
  const size_t H1SZ = big ? 46092288ull : 23046144ull;

  unsigned short* Vb      = (unsigned short*)(w);                // 11,523,072
  unsigned short* attnpre = (unsigned short*)(w + 11523072);     // 11,523,072 (= x_bf)
  float*          xf32    = (float*)(w + 23046144);              // 23,046,144
  unsigned short* h1      = (unsigned short*)(w + 46092288);     // H1SZ
  char*           tail    = w + 46092288 + H1SZ;
  float*          attw    = (float*)(tail);                      //  2,880,768
  unsigned*       offp    = (unsigned*)(tail + 2880768);         //    720,192
  unsigned short* Wv_t    = (unsigned short*)(tail + 3600960);   //    131,072
  unsigned short* Wo_t    = (unsigned short*)(tail + 3732032);   //    131,072
  unsigned short* W1_t    = (unsigned short*)(tail + 3863104);   //    524,288
  unsigned short* W2_t    = (unsigned short*)(tail + 4387392);   //    524,288
  unsigned short* x_bf    = attnpre;

  pre_kernel<<<dim3(728), 256, 0, stream>>>(
      m0, m1, m2, m3, pm_w, pm_b, Wv, Wo, W1, W2,
      Wv_t, Wo_t, W1_t, W2_t, offp, attw);

  // V = bf16(src @ Wv + bv), inline f32->bf16 A cast
  gemm_bres<0, true, 1><<<dim3(352, 1), 256, 0, stream>>>(
      src, (const short*)Wv_t, bv, nullptr, nullptr, nullptr,
      nullptr, Vb, TOK, 256);

  // deformable attention -> attnpre (bf16)
  sample_kernel<<<dim3(2814), 256, 0, stream>>>(
      Vb, refpts, offp, attw, attnpre);

  // x = LN1(attnpre @ Wo + bo + src) -> xf32 (f32) + x_bf (bf16, in place)
  gemm_bres<1, false, 1><<<dim3(352, 1), 256, 0, stream>>>(
      attnpre, (const short*)Wo_t, bo, src, ln1g, ln1b,
      xf32, x_bf, TOK, 256);

  if (big) {
    gemm_bres<2, false, 1><<<dim3(352, 4), 256, 0, stream>>>(
        x_bf, (const short*)W1_t, b1, nullptr, nullptr, nullptr,
        nullptr, h1, TOK, 1024);
    gemm_bres<3, false, 4><<<dim3(352, 1), 256, 0, stream>>>(
        h1, (const short*)W2_t, b2, xf32, ln2g, ln2b,
        out, nullptr, TOK, 256);
  } else {
    for (int ch = 0; ch < 2; ++ch) {
      const unsigned short* xc = x_bf + (size_t)ch * LEN_T * 256;
      const float*          xr = xf32 + (size_t)ch * LEN_T * 256;
      float*                oc = out  + (size_t)ch * LEN_T * 256;
      gemm_bres<2, false, 1><<<dim3(176, 4), 256, 0, stream>>>(
          xc, (const short*)W1_t, b1, nullptr, nullptr, nullptr,
          nullptr, h1, LEN_T, 1024);
      gemm_bres<3, false, 4><<<dim3(176, 1), 256, 0, stream>>>(
          h1, (const short*)W2_t, b2, xr, ln2g, ln2b,
          oc, nullptr, LEN_T, 256);
    }
  }
}

// Round 6
// 353.586 us; speedup vs baseline: 1.1826x; 1.1826x over previous
//
#include <hip/hip_runtime.h>
#include <cstddef>
#include <cstdint>

#define LEN_T 11253
#define TOK   22506     // BS * LEN
#define NHEADS 8
#define DMODEL 256

typedef __attribute__((ext_vector_type(8))) short short8;   // bf16x8 (4 VGPR)
typedef __attribute__((ext_vector_type(4))) float f32x4;

__device__ __forceinline__ unsigned short f2bf(float f) {
  union { float f; unsigned u; } v; v.f = f;
  unsigned r = v.u + 0x7fffu + ((v.u >> 16) & 1u);   // RNE
  return (unsigned short)(r >> 16);
}
__device__ __forceinline__ float bfhi2f(unsigned u) {
  union { unsigned u; float f; } v; v.u = u & 0xffff0000u; return v.f;
}
__device__ __forceinline__ float bflo2f(unsigned u) {
  union { unsigned u; float f; } v; v.u = u << 16; return v.f;
}
__device__ __forceinline__ void gld_lds16(const void* g, void* l) {
  __builtin_amdgcn_global_load_lds(
      (const __attribute__((address_space(1))) void*)g,
      (__attribute__((address_space(3))) void*)l, 16, 0, 0);
}

// branchless stable top-4 insert (desc, strict > : earlier index wins ties)
__device__ __forceinline__ void ins4(float v, int ji,
    float& t0, float& t1, float& t2, float& t3,
    int& i0, int& i1, int& i2, int& i3)
{
  bool a0 = v > t0, a1 = v > t1, a2 = v > t2, a3 = v > t3;
  t3 = a3 ? (a2 ? t2 : v) : t3;  i3 = a3 ? (a2 ? i2 : ji) : i3;
  t2 = a2 ? (a1 ? t1 : v) : t2;  i2 = a2 ? (a1 ? i1 : ji) : i2;
  t1 = a1 ? (a0 ? t0 : v) : t1;  i1 = a1 ? (a0 ? i0 : ji) : i1;
  t0 = a0 ? v : t0;              i0 = a0 ? ji : i0;
}

// ============ pre-kernel: per-(token,head) top-k + weight casts =============
// blocks [0,704): topk, one THREAD per (b,q,h) — 180k threads (round-4 form;
//   round-5's 88-block per-token scan was a 64x parallelism collapse: 112 µs
//   at 2.7% occupancy. Revert.)
// blocks [704,1344): weight cast+transpose, 4 elems/thread
__global__ __launch_bounds__(256) void pre_kernel(
    const float* __restrict__ m0, const float* __restrict__ m1,
    const float* __restrict__ m2, const float* __restrict__ m3,
    const float* __restrict__ pm_w, const float* __restrict__ pm_b,
    const float* __restrict__ Wv, const float* __restrict__ Wo,
    const float* __restrict__ W1, const float* __restrict__ W2,
    unsigned short* __restrict__ Wv_t, unsigned short* __restrict__ Wo_t,
    unsigned short* __restrict__ W1_t, unsigned short* __restrict__ W2_t,
    unsigned* __restrict__ offp, float* __restrict__ attw)
{
  int blk = blockIdx.x;
  if (blk >= 704) {   // ---- weight cast+transpose: Bt[n][k] = bf16(W[k][n])
    int cb = blk - 704;
    const float* W; unsigned short* Bt; int lk, ln, base;
    if (cb < 64)       { W = Wv; Bt = Wv_t; lk = 8;  ln = 8;  base = cb; }
    else if (cb < 128) { W = Wo; Bt = Wo_t; lk = 8;  ln = 8;  base = cb - 64; }
    else if (cb < 384) { W = W1; Bt = W1_t; lk = 8;  ln = 10; base = cb - 128; }
    else               { W = W2; Bt = W2_t; lk = 10; ln = 8;  base = cb - 384; }
    int i4 = (base * 256 + threadIdx.x) * 4;
    int n  = i4 >> lk;
    int k  = i4 & ((1 << lk) - 1);
    ushort4 o;
    o.x = f2bf(W[((size_t)(k + 0) << ln) + n]);
    o.y = f2bf(W[((size_t)(k + 1) << ln) + n]);
    o.z = f2bf(W[((size_t)(k + 2) << ln) + n]);
    o.w = f2bf(W[((size_t)(k + 3) << ln) + n]);
    *(ushort4*)(Bt + i4) = o;
    return;
  }
  // ---- top-k: one thread per (b, q, h) ----
  int t = blk * 256 + threadIdx.x;
  if (t >= TOK * NHEADS) return;
  int h  = t & 7;
  int bq = t >> 3;
  int b  = bq / LEN_T;
  int q  = bq - b * LEN_T;
  int l, H_, W_;
  const float* mk;
  if (q < 8464)       { l = 0; H_ = 92; W_ = 92; mk = m0; }
  else if (q < 10580) { l = 1; H_ = 46; W_ = 46; mk = m1; }
  else if (q < 11109) { l = 2; H_ = 23; W_ = 23; mk = m2; }
  else                { l = 3; H_ = 12; W_ = 12; mk = m3; }
  int st = (l == 0) ? 0 : (l == 1) ? 8464 : (l == 2) ? 10580 : 11109;
  int pos = q - st;
  int rr = pos / W_;
  int cc = pos - rr * W_;
  float w  = pm_w[l * NHEADS + h];
  float bb = pm_b[l * NHEADS + h];
  const float* mp = mk + (size_t)b * H_ * W_;

  float t0=-1e30f,t1=-1e30f,t2=-1e30f,t3=-1e30f;
  int   i0=0,i1=0,i2=0,i3=0;
  for (int i = 0; i < 7; ++i) {
    int yy = rr + i - 3;
    #pragma unroll
    for (int j = 0; j < 7; ++j) {
      int xx = cc + j - 3;
      float v = 0.f;                       // zero padding outside the map
      if (yy >= 0 && yy < H_ && xx >= 0 && xx < W_)
        v = mp[(size_t)yy * W_ + xx] * w + bb;
      ins4(v, j | (i << 4), t0, t1, t2, t3, i0, i1, i2, i3);
    }
  }
  // softmax over 16 = 4 values repeated 4x
  float e1 = __expf(t1 - t0);
  float e2 = __expf(t2 - t0);
  float e3 = __expf(t3 - t0);
  float inv = 1.f / (4.f * (1.f + e1 + e2 + e3));
  float4 wout; wout.x = inv; wout.y = e1 * inv; wout.z = e2 * inv; wout.w = e3 * inv;
  *(float4*)(attw + (size_t)t * 4) = wout;
  offp[t] = (unsigned)i0 | ((unsigned)i1 << 8)
          | ((unsigned)i2 << 16) | ((unsigned)i3 << 24);
}

// ---------------- deformable bilinear sampling (bf16 V, v2) ----------------
// 2 tokens per wave (8/block), 16B gathers, indices preloaded to registers.
// grid MUST be 2814 blocks; XCD-contiguous swizzle (8 XCDs, 2814 = 8*351+6).
__global__ __launch_bounds__(256, 3) void sample_kernel(
    const unsigned short* __restrict__ Vb, const float* __restrict__ refpts,
    const unsigned* __restrict__ offp, const float* __restrict__ attw,
    unsigned short* __restrict__ outp)
{
  __shared__ ushort4 sidx[4][2][128];   //  8 KB
  __shared__ float4  swgt[4][2][128];   // 16 KB
  const int wv   = threadIdx.x >> 6;
  const int lane = threadIdx.x & 63;
  const int bx = blockIdx.x & 7, by = blockIdx.x >> 3;
  const int nb = bx * 351 + min(bx, 6) + by;
  const int base = nb * 8;              // first token of this block

  #pragma unroll
  for (int e = 0; e < 4; ++e) {
    int g  = lane * 4 + e;              // 0..255
    int tk = g >> 7, t = g & 127;       // t = lp*8 + h
    int token = base + wv * 2 + tk;
    ushort4 idx; idx.x = 0; idx.y = 0; idx.z = 0; idx.w = 0;
    float4  wg;  wg.x = 0.f; wg.y = 0.f; wg.z = 0.f; wg.w = 0.f;
    if (token < TOK) {
      int h = t & 7, lp = t >> 3, lev = lp >> 2, p = lp & 3;
      int b = token >= LEN_T;
      unsigned pb = (offp[(size_t)token * 8 + h] >> (8 * p)) & 0xffu;
      float aw = attw[((size_t)token * 8 + h) * 4 + p];
      float ox = (float)(int)(pb & 15u) - 3.f;
      float oy = (float)(int)(pb >> 4)  - 3.f;
      int H_ = (lev == 0) ? 92 : (lev == 1) ? 46 : (lev == 2) ? 23 : 12;
      int st = (lev == 0) ? 0  : (lev == 1) ? 8464 : (lev == 2) ? 10580 : 11109;
      const float* rp = refpts + (size_t)token * 8;
      float xx = rp[2 * lev]     * (float)H_ - 0.5f + ox;
      float yy = rp[2 * lev + 1] * (float)H_ - 0.5f + oy;
      float x0f = floorf(xx), y0f = floorf(yy);
      float tx = xx - x0f, ty = yy - y0f;
      int x0 = (int)x0f, y0 = (int)y0f;
      int vbase = b * LEN_T + st;
      float wc[4] = {(1.f - tx) * (1.f - ty), tx * (1.f - ty),
                     (1.f - tx) * ty,         tx * ty};
      int xs[4] = {x0, x0 + 1, x0, x0 + 1};
      int ys[4] = {y0, y0, y0 + 1, y0 + 1};
      int id[4]; float wt[4];
      #pragma unroll
      for (int c = 0; c < 4; ++c) {
        int xi = xs[c], yi = ys[c];
        bool v_ = (xi >= 0) & (xi < H_) & (yi >= 0) & (yi < H_);
        id[c] = vbase + min(max(yi, 0), H_ - 1) * H_ + min(max(xi, 0), H_ - 1);
        wt[c] = v_ ? aw * wc[c] : 0.f;
      }
      idx.x = (unsigned short)id[0]; idx.y = (unsigned short)id[1];
      idx.z = (unsigned short)id[2]; idx.w = (unsigned short)id[3];
      wg.x = wt[0]; wg.y = wt[1]; wg.z = wt[2]; wg.w = wt[3];
    }
    sidx[wv][tk][t] = idx;
    swgt[wv][tk][t] = wg;
  }
  __syncthreads();

  const int tk2 = lane >> 5;
  const int h2  = (lane >> 2) & 7;
  const int dg  = lane & 3;
  const int token = base + wv * 2 + tk2;
  ushort4 si[16];
  #pragma unroll
  for (int lp = 0; lp < 16; ++lp) si[lp] = sidx[wv][tk2][lp * 8 + h2];
  const unsigned short* vb = Vb + h2 * 32 + dg * 8;   // 8 bf16 = 16B per lane
  f32x4 aA = {0.f, 0.f, 0.f, 0.f}, aB = {0.f, 0.f, 0.f, 0.f};
  #pragma unroll
  for (int lp = 0; lp < 16; ++lp) {
    float4 wg = swgt[wv][tk2][lp * 8 + h2];
    uint4 u0 = *(const uint4*)(vb + (size_t)si[lp].x * DMODEL);
    uint4 u1 = *(const uint4*)(vb + (size_t)si[lp].y * DMODEL);
    uint4 u2 = *(const uint4*)(vb + (size_t)si[lp].z * DMODEL);
    uint4 u3 = *(const uint4*)(vb + (size_t)si[lp].w * DMODEL);
    aA.x += wg.x*bflo2f(u0.x) + wg.y*bflo2f(u1.x) + wg.z*bflo2f(u2.x) + wg.w*bflo2f(u3.x);
    aA.y += wg.x*bfhi2f(u0.x) + wg.y*bfhi2f(u1.x) + wg.z*bfhi2f(u2.x) + wg.w*bfhi2f(u3.x);
    aA.z += wg.x*bflo2f(u0.y) + wg.y*bflo2f(u1.y) + wg.z*bflo2f(u2.y) + wg.w*bflo2f(u3.y);
    aA.w += wg.x*bfhi2f(u0.y) + wg.y*bfhi2f(u1.y) + wg.z*bfhi2f(u2.y) + wg.w*bfhi2f(u3.y);
    aB.x += wg.x*bflo2f(u0.z) + wg.y*bflo2f(u1.z) + wg.z*bflo2f(u2.z) + wg.w*bflo2f(u3.z);
    aB.y += wg.x*bfhi2f(u0.z) + wg.y*bfhi2f(u1.z) + wg.z*bfhi2f(u2.z) + wg.w*bfhi2f(u3.z);
    aB.z += wg.x*bflo2f(u0.w) + wg.y*bflo2f(u1.w) + wg.z*bflo2f(u2.w) + wg.w*bflo2f(u3.w);
    aB.w += wg.x*bfhi2f(u0.w) + wg.y*bfhi2f(u1.w) + wg.z*bfhi2f(u2.w) + wg.w*bfhi2f(u3.w);
  }
  if (token < TOK) {
    uint4 o;
    o.x = (unsigned)f2bf(aA.x) | ((unsigned)f2bf(aA.y) << 16);
    o.y = (unsigned)f2bf(aA.z) | ((unsigned)f2bf(aA.w) << 16);
    o.z = (unsigned)f2bf(aB.x) | ((unsigned)f2bf(aB.y) << 16);
    o.w = (unsigned)f2bf(aB.z) | ((unsigned)f2bf(aB.w) << 16);
    *(uint4*)(outp + (size_t)token * DMODEL + h2 * 32 + dg * 8) = o;
  }
}

// ============ B-resident MFMA GEMM, K = KC*256 ==============================
// C[M,N] = A[M,K] @ Bt[N,K]^T (+bias...). B fragments resident in VGPRs per
// 256-k chunk (8 kc x 4 nt x short8 = 128 VGPR); A double-buffered via LDS.
// Block = 64 rows x 256 cols, 4 waves, wave tile 64x64 (4x4 of 16x16x32).
// EPI 0: Cb = bf16(acc + bias)
// EPI 1: LN(acc + bias + res) -> C f32 AND Cb bf16   (N must be 256)
// EPI 2: Cb = bf16(relu(acc + bias))
// EPI 3: LN(acc + bias + res) -> C f32 only          (N must be 256)
// AF32: A is f32, cast to bf16 inline during staging.
template<int EPI, bool AF32, int KC>
__global__ __launch_bounds__(256, 2) void gemm_bres(
    const void* __restrict__ Aptr, const short* __restrict__ Bt,
    const float* __restrict__ bias, const float* __restrict__ res,
    const float* __restrict__ lng, const float* __restrict__ lnb,
    float* __restrict__ C, unsigned short* __restrict__ Cb,
    int M, int N)
{
  constexpr int K = KC * 256;
  __shared__ short As[2][64 * 32] __attribute__((aligned(16)));  // 2 x 4 KB
  __shared__ float2 lnred[64][4];
  const int tid  = threadIdx.x;
  const int w    = tid >> 6;
  const int lane = tid & 63;
  const int row0 = blockIdx.x * 64;
  const int wn   = blockIdx.y * 256 + w * 64;   // this wave's 64 output cols
  const int colq = lane & 15, quad = lane >> 4;
  const int kq8  = quad * 8;

  short8 bq[8][4];
  auto loadB = [&](int c) {
    #pragma unroll
    for (int kc = 0; kc < 8; ++kc)
      #pragma unroll
      for (int nt = 0; nt < 4; ++nt)
        bq[kc][nt] = *(const short8*)(Bt + (size_t)(wn + nt * 16 + colq) * K
                                         + c * 256 + kc * 32 + kq8);
  };

  f32x4 acc[4][4];
  #pragma unroll
  for (int i = 0; i < 4; ++i)
    #pragma unroll
    for (int j = 0; j < 4; ++j) acc[i][j] = (f32x4){0.f, 0.f, 0.f, 0.f};

  const int rA  = min(row0 + (tid >> 2), M - 1);
  const int kq4 = (tid & 3) * 8;
  const float* Af = (const float*)Aptr;
  const short* Ab = (const short*)Aptr;

  auto stageA = [&](int kbg, int nbuf) {
    if constexpr (AF32) {
      const float* ap = Af + (size_t)rA * K + kbg * 32 + kq4;
      float4 f0 = *(const float4*)ap;
      float4 f1 = *(const float4*)(ap + 4);
      uint4 u;
      u.x = (unsigned)f2bf(f0.x) | ((unsigned)f2bf(f0.y) << 16);
      u.y = (unsigned)f2bf(f0.z) | ((unsigned)f2bf(f0.w) << 16);
      u.z = (unsigned)f2bf(f1.x) | ((unsigned)f2bf(f1.y) << 16);
      u.w = (unsigned)f2bf(f1.z) | ((unsigned)f2bf(f1.w) << 16);
      *(uint4*)(As[nbuf] + (size_t)tid * 8) = u;
    } else {
      gld_lds16(Ab + (size_t)rA * K + kbg * 32 + kq4, As[nbuf] + (size_t)tid * 8);
    }
  };

  stageA(0, 0);
  loadB(0);
  __syncthreads();
  int buf = 0;
  #pragma unroll
  for (int c = 0; c < KC; ++c) {
    if (c > 0) loadB(c);
    #pragma unroll
    for (int kb = 0; kb < 8; ++kb) {
      const int kbg = c * 8 + kb;
      if (kbg < KC * 8 - 1) stageA(kbg + 1, buf ^ 1);
      short8 af[4];
      #pragma unroll
      for (int mt = 0; mt < 4; ++mt)
        af[mt] = *(const short8*)(As[buf] + (size_t)(mt * 16 + colq) * 32 + kq8);
      #pragma unroll
      for (int mt = 0; mt < 4; ++mt)
        #pragma unroll
        for (int nt = 0; nt < 4; ++nt)
          acc[mt][nt] = __builtin_amdgcn_mfma_f32_16x16x32_bf16(
              af[mt], bq[kb][nt], acc[mt][nt], 0, 0, 0);
      __syncthreads();
      buf ^= 1;
    }
  }

  // ---- epilogue: C/D layout col = lane&15, row = quad*4 + reg ----
  float bia[4];
  #pragma unroll
  for (int nt = 0; nt < 4; ++nt) bia[nt] = bias[wn + nt * 16 + colq];

  if constexpr (EPI == 1 || EPI == 3) {
    #pragma unroll
    for (int mt = 0; mt < 4; ++mt) {
      #pragma unroll
      for (int r = 0; r < 4; ++r) {
        int lrow = mt * 16 + quad * 4 + r;
        int rowc = min(row0 + lrow, M - 1);
        float s = 0.f, sq = 0.f;
        #pragma unroll
        for (int nt = 0; nt < 4; ++nt) {
          float f = acc[mt][nt][r] + bia[nt]
                  + res[(size_t)rowc * 256 + wn + nt * 16 + colq];
          acc[mt][nt][r] = f;
          s += f; sq += f * f;
        }
        #pragma unroll
        for (int off = 1; off < 16; off <<= 1) {
          s  += __shfl_xor(s,  off, 64);
          sq += __shfl_xor(sq, off, 64);
        }
        if (colq == 0) lnred[lrow][w] = (float2){s, sq};
      }
    }
    __syncthreads();
    #pragma unroll
    for (int mt = 0; mt < 4; ++mt) {
      #pragma unroll
      for (int r = 0; r < 4; ++r) {
        int lrow = mt * 16 + quad * 4 + r;
        int row  = row0 + lrow;
        if (row >= M) continue;
        float2 p0 = lnred[lrow][0], p1 = lnred[lrow][1];
        float2 p2 = lnred[lrow][2], p3 = lnred[lrow][3];
        float mu  = (p0.x + p1.x + p2.x + p3.x) * (1.f / 256.f);
        float var = (p0.y + p1.y + p2.y + p3.y) * (1.f / 256.f) - mu * mu;
        float rs  = rsqrtf(var + 1e-5f);          // biased var (jnp.var)
        #pragma unroll
        for (int nt = 0; nt < 4; ++nt) {
          int col = wn + nt * 16 + colq;
          float o = (acc[mt][nt][r] - mu) * rs * lng[col] + lnb[col];
          C[(size_t)row * 256 + col] = o;
          if constexpr (EPI == 1)
            Cb[(size_t)row * 256 + col] = f2bf(o);
        }
      }
    }
  } else {
    #pragma unroll
    for (int mt = 0; mt < 4; ++mt) {
      #pragma unroll
      for (int r = 0; r < 4; ++r) {
        int row = row0 + mt * 16 + quad * 4 + r;
        if (row < M) {
          #pragma unroll
          for (int nt = 0; nt < 4; ++nt) {
            float f = acc[mt][nt][r] + bia[nt];
            if constexpr (EPI == 2) f = fmaxf(f, 0.f);
            Cb[(size_t)row * N + wn + nt * 16 + colq] = f2bf(f);
          }
        }
      }
    }
  }
}

extern "C" void kernel_launch(void* const* d_in, const int* in_sizes, int n_in,
                              void* d_out, int out_size, void* d_ws, size_t ws_size,
                              hipStream_t stream)
{
  const float* src    = (const float*)d_in[0];
  const float* refpts = (const float*)d_in[2];
  const float* m0   = (const float*)d_in[4];
  const float* m1   = (const float*)d_in[5];
  const float* m2   = (const float*)d_in[6];
  const float* m3   = (const float*)d_in[7];
  const float* pm_w = (const float*)d_in[10];
  const float* pm_b = (const float*)d_in[11];
  const float* Wv   = (const float*)d_in[12];
  const float* bv   = (const float*)d_in[13];
  const float* Wo   = (const float*)d_in[14];
  const float* bo   = (const float*)d_in[15];
  const float* ln1g = (const float*)d_in[16];
  const float* ln1b = (const float*)d_in[17];
  const float* W1   = (const float*)d_in[18];
  const float* b1   = (const float*)d_in[19];
  const float* W2   = (const float*)d_in[20];
  const float* b2   = (const float*)d_in[21];
  const float* ln2g = (const float*)d_in[22];
  const float* ln2b = (const float*)d_in[23];
  float* out = (float*)d_out;
  char*  w   = (char*)d_ws;

  const bool big = ws_size >= 97096256ull;          // full-batch h1
  const size_t H1SZ = big ? 46092288ull : 23046144ull;

  unsigned short* Vb      = (unsigned short*)(w);                // 11,523,072
  unsigned short* attnpre = (unsigned short*)(w + 11523072);     // 11,523,072 (= x_bf)
  float*          xf32    = (float*)(w + 23046144);              // 23,046,144
  unsigned short* h1      = (unsigned short*)(w + 46092288);     // H1SZ
  char*           tail    = w + 46092288 + H1SZ;
  float*          attw    = (float*)(tail);                      //  2,880,768
  unsigned*       offp    = (unsigned*)(tail + 2880768);         //    720,192
  unsigned short* Wv_t    = (unsigned short*)(tail + 3600960);   //    131,072
  unsigned short* Wo_t    = (unsigned short*)(tail + 3732032);   //    131,072
  unsigned short* W1_t    = (unsigned short*)(tail + 3863104);   //    524,288
  unsigned short* W2_t    = (unsigned short*)(tail + 4387392);   //    524,288
  unsigned short* x_bf    = attnpre;

  pre_kernel<<<dim3(1344), 256, 0, stream>>>(
      m0, m1, m2, m3, pm_w, pm_b, Wv, Wo, W1, W2,
      Wv_t, Wo_t, W1_t, W2_t, offp, attw);

  // V = bf16(src @ Wv + bv), inline f32->bf16 A cast
  gemm_bres<0, true, 1><<<dim3(352, 1), 256, 0, stream>>>(
      src, (const short*)Wv_t, bv, nullptr, nullptr, nullptr,
      nullptr, Vb, TOK, 256);

  // deformable attention -> attnpre (bf16)
  sample_kernel<<<dim3(2814), 256, 0, stream>>>(
      Vb, refpts, offp, attw, attnpre);

  // x = LN1(attnpre @ Wo + bo + src) -> xf32 (f32) + x_bf (bf16, in place)
  gemm_bres<1, false, 1><<<dim3(352, 1), 256, 0, stream>>>(
      attnpre, (const short*)Wo_t, bo, src, ln1g, ln1b,
      xf32, x_bf, TOK, 256);

  if (big) {
    gemm_bres<2, false, 1><<<dim3(352, 4), 256, 0, stream>>>(
        x_bf, (const short*)W1_t, b1, nullptr, nullptr, nullptr,
        nullptr, h1, TOK, 1024);
    gemm_bres<3, false, 4><<<dim3(352, 1), 256, 0, stream>>>(
        h1, (const short*)W2_t, b2, xf32, ln2g, ln2b,
        out, nullptr, TOK, 256);
  } else {
    for (int ch = 0; ch < 2; ++ch) {
      const unsigned short* xc = x_bf + (size_t)ch * LEN_T * 256;
      const float*          xr = xf32 + (size_t)ch * LEN_T * 256;
      float*                oc = out  + (size_t)ch * LEN_T * 256;
      gemm_bres<2, false, 1><<<dim3(176, 4), 256, 0, stream>>>(
          xc, (const short*)W1_t, b1, nullptr, nullptr, nullptr,
          nullptr, h1, LEN_T, 1024);
      gemm_bres<3, false, 4><<<dim3(176, 1), 256, 0, stream>>>(
          h1, (const short*)W2_t, b2, xr, ln2g, ln2b,
          oc, nullptr, LEN_T, 256);
    }
  }
}

// Round 9
// 322.258 us; speedup vs baseline: 1.2976x; 1.0972x over previous
//
#include <hip/hip_runtime.h>
#include <cstddef>
#include <cstdint>

#define LEN_T 11253
#define TOK   22506     // BS * LEN
#define NHEADS 8
#define DMODEL 256

typedef __attribute__((ext_vector_type(8))) short short8;   // bf16x8 (4 VGPR)
typedef __attribute__((ext_vector_type(4))) float f32x4;

__device__ __forceinline__ unsigned short f2bf(float f) {
  union { float f; unsigned u; } v; v.f = f;
  unsigned r = v.u + 0x7fffu + ((v.u >> 16) & 1u);   // RNE
  return (unsigned short)(r >> 16);
}
__device__ __forceinline__ float bfhi2f(unsigned u) {
  union { unsigned u; float f; } v; v.u = u & 0xffff0000u; return v.f;
}
__device__ __forceinline__ float bflo2f(unsigned u) {
  union { unsigned u; float f; } v; v.u = u << 16; return v.f;
}
__device__ __forceinline__ float bf2f(unsigned short s) {
  union { unsigned u; float f; } v; v.u = (unsigned)s << 16; return v.f;
}
__device__ __forceinline__ void gld_lds16(const void* g, void* l) {
  __builtin_amdgcn_global_load_lds(
      (const __attribute__((address_space(1))) void*)g,
      (__attribute__((address_space(3))) void*)l, 16, 0, 0);
}

// branchless stable top-4 insert (desc, strict > : earlier index wins ties)
__device__ __forceinline__ void ins4(float v, int ji,
    float& t0, float& t1, float& t2, float& t3,
    int& i0, int& i1, int& i2, int& i3)
{
  bool a0 = v > t0, a1 = v > t1, a2 = v > t2, a3 = v > t3;
  t3 = a3 ? (a2 ? t2 : v) : t3;  i3 = a3 ? (a2 ? i2 : ji) : i3;
  t2 = a2 ? (a1 ? t1 : v) : t2;  i2 = a2 ? (a1 ? i1 : ji) : i2;
  t1 = a1 ? (a0 ? t0 : v) : t1;  i1 = a1 ? (a0 ? i0 : ji) : i1;
  t0 = a0 ? v : t0;              i0 = a0 ? ji : i0;
}

// ============ pre-kernel: per-(token,head) top-k + weight casts =============
// blocks [0,704): topk, one THREAD per (b,q,h)
// blocks [704,1344): weight cast+transpose, 4 elems/thread
__global__ __launch_bounds__(256) void pre_kernel(
    const float* __restrict__ m0, const float* __restrict__ m1,
    const float* __restrict__ m2, const float* __restrict__ m3,
    const float* __restrict__ pm_w, const float* __restrict__ pm_b,
    const float* __restrict__ Wv, const float* __restrict__ Wo,
    const float* __restrict__ W1, const float* __restrict__ W2,
    unsigned short* __restrict__ Wv_t, unsigned short* __restrict__ Wo_t,
    unsigned short* __restrict__ W1_t, unsigned short* __restrict__ W2_t,
    unsigned* __restrict__ offp, float* __restrict__ attw)
{
  int blk = blockIdx.x;
  if (blk >= 704) {   // ---- weight cast+transpose: Bt[n][k] = bf16(W[k][n])
    int cb = blk - 704;
    const float* W; unsigned short* Bt; int lk, ln, base;
    if (cb < 64)       { W = Wv; Bt = Wv_t; lk = 8;  ln = 8;  base = cb; }
    else if (cb < 128) { W = Wo; Bt = Wo_t; lk = 8;  ln = 8;  base = cb - 64; }
    else if (cb < 384) { W = W1; Bt = W1_t; lk = 8;  ln = 10; base = cb - 128; }
    else               { W = W2; Bt = W2_t; lk = 10; ln = 8;  base = cb - 384; }
    int i4 = (base * 256 + threadIdx.x) * 4;
    int n  = i4 >> lk;
    int k  = i4 & ((1 << lk) - 1);
    ushort4 o;
    o.x = f2bf(W[((size_t)(k + 0) << ln) + n]);
    o.y = f2bf(W[((size_t)(k + 1) << ln) + n]);
    o.z = f2bf(W[((size_t)(k + 2) << ln) + n]);
    o.w = f2bf(W[((size_t)(k + 3) << ln) + n]);
    *(ushort4*)(Bt + i4) = o;
    return;
  }
  // ---- top-k: one thread per (b, q, h) ----
  int t = blk * 256 + threadIdx.x;
  if (t >= TOK * NHEADS) return;
  int h  = t & 7;
  int bq = t >> 3;
  int b  = bq / LEN_T;
  int q  = bq - b * LEN_T;
  int l, H_, W_;
  const float* mk;
  if (q < 8464)       { l = 0; H_ = 92; W_ = 92; mk = m0; }
  else if (q < 10580) { l = 1; H_ = 46; W_ = 46; mk = m1; }
  else if (q < 11109) { l = 2; H_ = 23; W_ = 23; mk = m2; }
  else                { l = 3; H_ = 12; W_ = 12; mk = m3; }
  int st = (l == 0) ? 0 : (l == 1) ? 8464 : (l == 2) ? 10580 : 11109;
  int pos = q - st;
  int rr = pos / W_;
  int cc = pos - rr * W_;
  float w  = pm_w[l * NHEADS + h];
  float bb = pm_b[l * NHEADS + h];
  const float* mp = mk + (size_t)b * H_ * W_;

  float t0=-1e30f,t1=-1e30f,t2=-1e30f,t3=-1e30f;
  int   i0=0,i1=0,i2=0,i3=0;
  for (int i = 0; i < 7; ++i) {
    int yy = rr + i - 3;
    #pragma unroll
    for (int j = 0; j < 7; ++j) {
      int xx = cc + j - 3;
      float v = 0.f;                       // zero padding outside the map
      if (yy >= 0 && yy < H_ && xx >= 0 && xx < W_)
        v = mp[(size_t)yy * W_ + xx] * w + bb;
      ins4(v, j | (i << 4), t0, t1, t2, t3, i0, i1, i2, i3);
    }
  }
  float e1 = __expf(t1 - t0);
  float e2 = __expf(t2 - t0);
  float e3 = __expf(t3 - t0);
  float inv = 1.f / (4.f * (1.f + e1 + e2 + e3));
  float4 wout; wout.x = inv; wout.y = e1 * inv; wout.z = e2 * inv; wout.w = e3 * inv;
  *(float4*)(attw + (size_t)t * 4) = wout;
  offp[t] = (unsigned)i0 | ((unsigned)i1 << 8)
          | ((unsigned)i2 << 16) | ((unsigned)i3 << 24);
}

// ---------------- deformable bilinear sampling (bf16 V, v1) ----------------
// one wave per token; XCD-contiguous token swizzle for L2 locality.
// grid MUST be 5627 blocks (= 8*703 + 3).
__global__ __launch_bounds__(256) void sample_kernel(
    const unsigned short* __restrict__ Vb, const float* __restrict__ refpts,
    const unsigned* __restrict__ offp, const float* __restrict__ attw,
    unsigned short* __restrict__ outp)
{
  __shared__ int4  sidx[4][128];
  __shared__ float4 swgt[4][128];
  const int wv   = threadIdx.x >> 6;
  const int lane = threadIdx.x & 63;
  const int bx = blockIdx.x & 7, by = blockIdx.x >> 3;
  const int nb = bx * 703 + min(bx, 3) + by;
  const int blk = nb * 4 + wv;             // b*LEN + q
  const bool ok = blk < TOK;

  if (ok) {
    const int b = (blk >= LEN_T) ? 1 : 0;
    const float* rp = refpts + (size_t)blk * 8;
    #pragma unroll
    for (int e = 0; e < 2; ++e) {
      int t = lane * 2 + e;                // t = lp*8 + h
      int h = t & 7, lp = t >> 3;
      int l = lp >> 2, p = lp & 3;
      unsigned pb = (offp[(size_t)blk * 8 + h] >> (8 * p)) & 0xffu;
      float ox = (float)(int)(pb & 15u) - 3.f;
      float oy = (float)(int)(pb >> 4)  - 3.f;
      float aw = attw[((size_t)blk * 8 + h) * 4 + p];
      int H_ = (l == 0) ? 92 : (l == 1) ? 46 : (l == 2) ? 23 : 12;
      int st = (l == 0) ? 0  : (l == 1) ? 8464 : (l == 2) ? 10580 : 11109;
      float xx = rp[2 * l]     * (float)H_ - 0.5f + ox;
      float yy = rp[2 * l + 1] * (float)H_ - 0.5f + oy;
      float x0f = floorf(xx), y0f = floorf(yy);
      float tx = xx - x0f, ty = yy - y0f;
      int x0 = (int)x0f, y0 = (int)y0f;
      int base = b * LEN_T + st;
      float wc[4] = {(1.f - tx) * (1.f - ty), tx * (1.f - ty),
                     (1.f - tx) * ty,         tx * ty};
      int4 idx; float4 wg;
      int xs[4] = {x0, x0 + 1, x0, x0 + 1};
      int ys[4] = {y0, y0, y0 + 1, y0 + 1};
      int   id[4]; float wgt[4];
      #pragma unroll
      for (int c = 0; c < 4; ++c) {
        int xi = xs[c], yi = ys[c];
        bool v_ = (xi >= 0) & (xi < H_) & (yi >= 0) & (yi < H_);
        id[c]  = base + min(max(yi, 0), H_ - 1) * H_ + min(max(xi, 0), H_ - 1);
        wgt[c] = v_ ? aw * wc[c] : 0.f;
      }
      idx.x = id[0]; idx.y = id[1]; idx.z = id[2]; idx.w = id[3];
      wg.x = wgt[0]; wg.y = wgt[1]; wg.z = wgt[2]; wg.w = wgt[3];
      sidx[wv][t] = idx;
      swgt[wv][t] = wg;
    }
  }
  __syncthreads();

  if (ok) {
    const int h = lane >> 3, dg = lane & 7;
    const unsigned short* vb = Vb + h * 32 + dg * 4;   // 4 bf16 = 8B per lane
    f32x4 acc = {0.f, 0.f, 0.f, 0.f};
    #pragma unroll 4
    for (int lp = 0; lp < 16; ++lp) {
      int4  idx = sidx[wv][lp * 8 + h];
      float4 wg = swgt[wv][lp * 8 + h];
      uint2 u0 = *(const uint2*)(vb + (size_t)idx.x * DMODEL);
      uint2 u1 = *(const uint2*)(vb + (size_t)idx.y * DMODEL);
      uint2 u2 = *(const uint2*)(vb + (size_t)idx.z * DMODEL);
      uint2 u3 = *(const uint2*)(vb + (size_t)idx.w * DMODEL);
      acc.x += wg.x * bflo2f(u0.x) + wg.y * bflo2f(u1.x) + wg.z * bflo2f(u2.x) + wg.w * bflo2f(u3.x);
      acc.y += wg.x * bfhi2f(u0.x) + wg.y * bfhi2f(u1.x) + wg.z * bfhi2f(u2.x) + wg.w * bfhi2f(u3.x);
      acc.z += wg.x * bflo2f(u0.y) + wg.y * bflo2f(u1.y) + wg.z * bflo2f(u2.y) + wg.w * bflo2f(u3.y);
      acc.w += wg.x * bfhi2f(u0.y) + wg.y * bfhi2f(u1.y) + wg.z * bfhi2f(u2.y) + wg.w * bfhi2f(u3.y);
    }
    uint2 o;
    o.x = (unsigned)f2bf(acc.x) | ((unsigned)f2bf(acc.y) << 16);
    o.y = (unsigned)f2bf(acc.z) | ((unsigned)f2bf(acc.w) << 16);
    *(uint2*)(outp + (size_t)blk * DMODEL + h * 32 + dg * 4) = o;
  }
}

// ============ B-resident MFMA GEMM, K = KC*256 (benched r5/r6) ==============
// C[M,N] = A[M,K] @ Bt[N,K]^T (+bias...). B fragments resident in VGPRs per
// 256-k chunk; A double-buffered via 2x4KB LDS. Block = 64 rows x 256 cols.
// EPI 0: Cb = bf16(acc + bias)
// EPI 1: LN(acc + bias + res_f32) -> Cb bf16 only    (N must be 256)
// EPI 2: Cb = bf16(relu(acc + bias))
// EPI 3: LN(acc + bias + resb_bf16) -> C f32 only    (N must be 256)
// AF32: A is f32, cast to bf16 inline during staging.
template<int EPI, bool AF32, int KC>
__global__ __launch_bounds__(256, 2) void gemm_bres(
    const void* __restrict__ Aptr, const short* __restrict__ Bt,
    const float* __restrict__ bias, const float* __restrict__ res,
    const unsigned short* __restrict__ resb,
    const float* __restrict__ lng, const float* __restrict__ lnb,
    float* __restrict__ C, unsigned short* __restrict__ Cb,
    int M, int N)
{
  constexpr int K = KC * 256;
  __shared__ short As[2][64 * 32] __attribute__((aligned(16)));  // 2 x 4 KB
  __shared__ float2 lnred[64][4];
  const int tid  = threadIdx.x;
  const int w    = tid >> 6;
  const int lane = tid & 63;
  const int row0 = blockIdx.x * 64;
  const int wn   = blockIdx.y * 256 + w * 64;   // this wave's 64 output cols
  const int colq = lane & 15, quad = lane >> 4;
  const int kq8  = quad * 8;

  short8 bq[8][4];
  auto loadB = [&](int c) {
    #pragma unroll
    for (int kc = 0; kc < 8; ++kc)
      #pragma unroll
      for (int nt = 0; nt < 4; ++nt)
        bq[kc][nt] = *(const short8*)(Bt + (size_t)(wn + nt * 16 + colq) * K
                                         + c * 256 + kc * 32 + kq8);
  };

  f32x4 acc[4][4];
  #pragma unroll
  for (int i = 0; i < 4; ++i)
    #pragma unroll
    for (int j = 0; j < 4; ++j) acc[i][j] = (f32x4){0.f, 0.f, 0.f, 0.f};

  const int rA  = min(row0 + (tid >> 2), M - 1);
  const int kq4 = (tid & 3) * 8;
  const float* Af = (const float*)Aptr;
  const short* Ab = (const short*)Aptr;

  auto stageA = [&](int kbg, int nbuf) {
    if constexpr (AF32) {
      const float* ap = Af + (size_t)rA * K + kbg * 32 + kq4;
      float4 f0 = *(const float4*)ap;
      float4 f1 = *(const float4*)(ap + 4);
      uint4 u;
      u.x = (unsigned)f2bf(f0.x) | ((unsigned)f2bf(f0.y) << 16);
      u.y = (unsigned)f2bf(f0.z) | ((unsigned)f2bf(f0.w) << 16);
      u.z = (unsigned)f2bf(f1.x) | ((unsigned)f2bf(f1.y) << 16);
      u.w = (unsigned)f2bf(f1.z) | ((unsigned)f2bf(f1.w) << 16);
      *(uint4*)(As[nbuf] + (size_t)tid * 8) = u;
    } else {
      gld_lds16(Ab + (size_t)rA * K + kbg * 32 + kq4, As[nbuf] + (size_t)tid * 8);
    }
  };

  stageA(0, 0);
  loadB(0);
  __syncthreads();
  int buf = 0;
  #pragma unroll
  for (int c = 0; c < KC; ++c) {
    if (c > 0) loadB(c);
    #pragma unroll
    for (int kb = 0; kb < 8; ++kb) {
      const int kbg = c * 8 + kb;
      if (kbg < KC * 8 - 1) stageA(kbg + 1, buf ^ 1);
      short8 af[4];
      #pragma unroll
      for (int mt = 0; mt < 4; ++mt)
        af[mt] = *(const short8*)(As[buf] + (size_t)(mt * 16 + colq) * 32 + kq8);
      #pragma unroll
      for (int mt = 0; mt < 4; ++mt)
        #pragma unroll
        for (int nt = 0; nt < 4; ++nt)
          acc[mt][nt] = __builtin_amdgcn_mfma_f32_16x16x32_bf16(
              af[mt], bq[kb][nt], acc[mt][nt], 0, 0, 0);
      __syncthreads();
      buf ^= 1;
    }
  }

  // ---- epilogue: C/D layout col = lane&15, row = quad*4 + reg ----
  float bia[4];
  #pragma unroll
  for (int nt = 0; nt < 4; ++nt) bia[nt] = bias[wn + nt * 16 + colq];

  if constexpr (EPI == 1 || EPI == 3) {
    #pragma unroll
    for (int mt = 0; mt < 4; ++mt) {
      #pragma unroll
      for (int r = 0; r < 4; ++r) {
        int lrow = mt * 16 + quad * 4 + r;
        int rowc = min(row0 + lrow, M - 1);
        float s = 0.f, sq = 0.f;
        #pragma unroll
        for (int nt = 0; nt < 4; ++nt) {
          float rv;
          if constexpr (EPI == 1)
            rv = res[(size_t)rowc * 256 + wn + nt * 16 + colq];
          else
            rv = bf2f(resb[(size_t)rowc * 256 + wn + nt * 16 + colq]);
          float f = acc[mt][nt][r] + bia[nt] + rv;
          acc[mt][nt][r] = f;
          s += f; sq += f * f;
        }
        #pragma unroll
        for (int off = 1; off < 16; off <<= 1) {
          s  += __shfl_xor(s,  off, 64);
          sq += __shfl_xor(sq, off, 64);
        }
        if (colq == 0) lnred[lrow][w] = (float2){s, sq};
      }
    }
    __syncthreads();
    #pragma unroll
    for (int mt = 0; mt < 4; ++mt) {
      #pragma unroll
      for (int r = 0; r < 4; ++r) {
        int lrow = mt * 16 + quad * 4 + r;
        int row  = row0 + lrow;
        if (row >= M) continue;
        float2 p0 = lnred[lrow][0], p1 = lnred[lrow][1];
        float2 p2 = lnred[lrow][2], p3 = lnred[lrow][3];
        float mu  = (p0.x + p1.x + p2.x + p3.x) * (1.f / 256.f);
        float var = (p0.y + p1.y + p2.y + p3.y) * (1.f / 256.f) - mu * mu;
        float rs  = rsqrtf(var + 1e-5f);          // biased var (jnp.var)
        #pragma unroll
        for (int nt = 0; nt < 4; ++nt) {
          int col = wn + nt * 16 + colq;
          float o = (acc[mt][nt][r] - mu) * rs * lng[col] + lnb[col];
          if constexpr (EPI == 1)
            Cb[(size_t)row * 256 + col] = f2bf(o);
          else
            C[(size_t)row * 256 + col] = o;
        }
      }
    }
  } else {
    #pragma unroll
    for (int mt = 0; mt < 4; ++mt) {
      #pragma unroll
      for (int r = 0; r < 4; ++r) {
        int row = row0 + mt * 16 + quad * 4 + r;
        if (row < M) {
          #pragma unroll
          for (int nt = 0; nt < 4; ++nt) {
            float f = acc[mt][nt][r] + bia[nt];
            if constexpr (EPI == 2) f = fmaxf(f, 0.f);
            Cb[(size_t)row * N + wn + nt * 16 + colq] = f2bf(f);
          }
        }
      }
    }
  }
}

extern "C" void kernel_launch(void* const* d_in, const int* in_sizes, int n_in,
                              void* d_out, int out_size, void* d_ws, size_t ws_size,
                              hipStream_t stream)
{
  const float* src    = (const float*)d_in[0];
  const float* refpts = (const float*)d_in[2];
  const float* m0   = (const float*)d_in[4];
  const float* m1   = (const float*)d_in[5];
  const float* m2   = (const float*)d_in[6];
  const float* m3   = (const float*)d_in[7];
  const float* pm_w = (const float*)d_in[10];
  const float* pm_b = (const float*)d_in[11];
  const float* Wv   = (const float*)d_in[12];
  const float* bv   = (const float*)d_in[13];
  const float* Wo   = (const float*)d_in[14];
  const float* bo   = (const float*)d_in[15];
  const float* ln1g = (const float*)d_in[16];
  const float* ln1b = (const float*)d_in[17];
  const float* W1   = (const float*)d_in[18];
  const float* b1   = (const float*)d_in[19];
  const float* W2   = (const float*)d_in[20];
  const float* b2   = (const float*)d_in[21];
  const float* ln2g = (const float*)d_in[22];
  const float* ln2b = (const float*)d_in[23];
  float* out = (float*)d_out;
  char*  w   = (char*)d_ws;

  // workspace (74.05 MB total — same footprint the round-4/6 benches ran in):
  unsigned short* Vb      = (unsigned short*)(w);                // 11,523,072
  unsigned short* attnpre = (unsigned short*)(w + 11523072);     // 11,523,072 (= x_bf)
  unsigned short* h1      = (unsigned short*)(w + 23046144);     // 46,092,288
  char*           tail    = w + 69138432;
  float*          attw    = (float*)(tail);                      //  2,880,768
  unsigned*       offp    = (unsigned*)(tail + 2880768);         //    720,192
  unsigned short* Wv_t    = (unsigned short*)(tail + 3600960);   //    131,072
  unsigned short* Wo_t    = (unsigned short*)(tail + 3732032);   //    131,072
  unsigned short* W1_t    = (unsigned short*)(tail + 3863104);   //    524,288
  unsigned short* W2_t    = (unsigned short*)(tail + 4387392);   //    524,288
  unsigned short* x_bf    = attnpre;

  pre_kernel<<<dim3(1344), 256, 0, stream>>>(
      m0, m1, m2, m3, pm_w, pm_b, Wv, Wo, W1, W2,
      Wv_t, Wo_t, W1_t, W2_t, offp, attw);

  // V = bf16(src @ Wv + bv), inline f32->bf16 A cast
  gemm_bres<0, true, 1><<<dim3(352, 1), 256, 0, stream>>>(
      src, (const short*)Wv_t, bv, nullptr, nullptr, nullptr, nullptr,
      nullptr, Vb, TOK, 256);

  // deformable attention -> attnpre (bf16)
  sample_kernel<<<dim3(5627), 256, 0, stream>>>(
      Vb, refpts, offp, attw, attnpre);

  // x_bf = bf16(LN1(attnpre @ Wo + bo + src))  (in-place block-local rewrite)
  gemm_bres<1, false, 1><<<dim3(352, 1), 256, 0, stream>>>(
      attnpre, (const short*)Wo_t, bo, src, nullptr, ln1g, ln1b,
      nullptr, x_bf, TOK, 256);

  // h1 = bf16(relu(x_bf @ W1 + b1))
  gemm_bres<2, false, 1><<<dim3(352, 4), 256, 0, stream>>>(
      x_bf, (const short*)W1_t, b1, nullptr, nullptr, nullptr, nullptr,
      nullptr, h1, TOK, 1024);

  // out = LN2(h1 @ W2 + b2 + x_bf)
  gemm_bres<3, false, 4><<<dim3(352, 1), 256, 0, stream>>>(
      h1, (const short*)W2_t, b2, nullptr, x_bf, ln2g, ln2b,
      out, nullptr, TOK, 256);
}